// Round 12
// baseline (63.267 us; speedup 1.0000x reference)
//
#include <hip/hip_runtime.h>
#include <math.h>

#define NB 64
#define NP 784      // 28*28
#define ND 512
#define NK 64
#define EPS_F 1e-12f

typedef float f32x4 __attribute__((ext_vector_type(4)));
typedef short bf16x8 __attribute__((ext_vector_type(8)));

// Leading barrier: memory-clobber fences pin all LDS/global memory ops.
#define BAR_HEAD() { asm volatile("" ::: "memory"); \
                     __builtin_amdgcn_s_barrier(); \
                     asm volatile("" ::: "memory"); }
// Trailing barrier: rule #18 — "memory" does NOT order register-only MFMA;
// sched_barrier(0) blocks ALL migration; lgkmcnt(0) drains the LDS pipe
// before any wave crosses.
#define BAR_TAIL() { __builtin_amdgcn_sched_barrier(0); \
                     asm volatile("s_waitcnt lgkmcnt(0)" ::: "memory"); \
                     __builtin_amdgcn_sched_barrier(0); \
                     __builtin_amdgcn_s_barrier(); \
                     __builtin_amdgcn_sched_barrier(0); }
#define VMCNT(n) asm volatile("s_waitcnt vmcnt(" #n ")" ::: "memory")

__device__ __forceinline__ unsigned short f2bf(float f) {
    unsigned u = __builtin_bit_cast(unsigned, f);
    u += 0x7fffu + ((u >> 16) & 1u);
    return (unsigned short)(u >> 16);
}

__device__ __forceinline__ unsigned cvt_pk_bf16(float lo, float hi) {
    unsigned r;
    asm("v_cvt_pk_bf16_f32 %0, %1, %2" : "=v"(r) : "v"(lo), "v"(hi));
    return r;
}

__device__ __forceinline__ float bf2f(unsigned short u) {
    unsigned x = (unsigned)u << 16;
    return __builtin_bit_cast(float, x);
}

__device__ __forceinline__ bf16x8 pack8(const float* s) {
    union { unsigned u[4]; bf16x8 v; } r;
#pragma unroll
    for (int i = 0; i < 4; ++i) r.u[i] = cvt_pk_bf16(s[2 * i], s[2 * i + 1]);
    return r.v;
}

// async 16B global->LDS (dest wave-uniform; HW adds lane*16)
__device__ __forceinline__ void gload16(const void* g, void* l) {
    __builtin_amdgcn_global_load_lds(
        (const __attribute__((address_space(1))) unsigned*)g,
        (__attribute__((address_space(3))) unsigned*)l, 16, 0, 0);
}

// ---------------------------------------------------------------------------
// K0: Wt[k][d] bf16 = W[d][k] fp32; zero zpad.
// ---------------------------------------------------------------------------
__global__ __launch_bounds__(256) void k_wt(const float* __restrict__ W,
                                            unsigned short* __restrict__ Wt,
                                            float* __restrict__ zpad)
{
    int idx = blockIdx.x * 256 + threadIdx.x;   // 0..32767
    int k = idx >> 9, d = idx & 511;
    Wt[idx] = f2bf(W[(size_t)d * NK + k]);
    if (idx < 64) zpad[idx] = 0.f;
}

// ---------------------------------------------------------------------------
// K1: s = x.W + bias ; a = softmax_k(s) ; aT[b][k][n] bf16 ;
// a_sum_p[b][blk][k] (deterministic partials). grid (13,64), 4 waves.
// Tile 64n x 64k, BK=32, 16 steps, TRIPLE-buffered gload_lds staging.
// LDS 36.9KB -> 4 blocks/CU (all 832 co-resident).
// ---------------------------------------------------------------------------
__global__ __launch_bounds__(256) void k_assign(
    const float* __restrict__ x, const unsigned short* __restrict__ Wt,
    const float* __restrict__ bias, unsigned short* __restrict__ aT,
    float* __restrict__ a_sum_p)
{
    // [0,24576) xbuf x3 (8KB each) | [24576,36864) wbuf x3 (4KB each)
    __shared__ __align__(16) char lds[36864];
    __shared__ float asw[4][64];

    const int t = threadIdx.x;
    const int w = t >> 6, l = t & 63, lr = l & 15, lg = l >> 4;
    const int b = blockIdx.y, n0 = blockIdx.x * 64;

    const float* xb = x + (size_t)b * NP * ND;

    auto STAGE = [&](int d0, int buf) {
        char* xdst = lds + buf * 8192 + w * 1024;
        char* wdst = lds + 24576 + buf * 4096 + w * 1024;
#pragma unroll
        for (int i = 0; i < 2; ++i) {            // x tile: [64n][8 chunks] fp32
            int flat = t + i * 256;
            int n = flat >> 3, c = flat & 7;
            int cs = c ^ (n & 7);
            int ng = n0 + n; if (ng >= NP) ng = NP - 1;   // dup rows discarded later
            gload16(xb + (size_t)ng * ND + d0 + cs * 4, xdst + i * 4096);
        }
        {                                         // Wt tile: [64k][4 chunks] bf16
            int k = t >> 2, c = t & 3;
            int cs = c ^ (k & 3);
            gload16(Wt + (size_t)k * ND + d0 + cs * 8, wdst);
        }
    };

    f32x4 acc[4] = {};
    STAGE(0, 0);
    STAGE(32, 1);
#pragma unroll
    for (int s = 0; s < 16; ++s) {
        if (s < 14)      { STAGE((s + 2) * 32, (s + 2) % 3); VMCNT(6); }
        else if (s == 14) { VMCNT(3); }
        else              { VMCNT(0); }
        BAR_HEAD();                              // buf[s%3] ready for all waves
        const char* xT = lds + (s % 3) * 8192;
        const char* wT = lds + 24576 + (s % 3) * 4096;
        const int nr = w * 16 + lr;
        const int cc = lg * 2;
        float av[8];
        *(f32x4*)&av[0] = *(const f32x4*)(xT + nr * 128 + ((cc ^ (nr & 7)) * 16));
        *(f32x4*)&av[4] = *(const f32x4*)(xT + nr * 128 + (((cc + 1) ^ (nr & 7)) * 16));
        bf16x8 af = pack8(av);
#pragma unroll
        for (int kf = 0; kf < 4; ++kf) {
            int kr = kf * 16 + lr;
            bf16x8 bfr = *(const bf16x8*)(wT + kr * 64 + ((lg ^ (kr & 3)) * 16));
            acc[kf] = __builtin_amdgcn_mfma_f32_16x16x32_bf16(af, bfr, acc[kf], 0, 0, 0);
        }
        BAR_TAIL();                              // drain LDS pipe, then barrier
    }

    // softmax over k: lane holds k = kf*16+lr, n = n0 + w*16 + lg*4 + r
    float pv[4][4];
    float part[4] = {0.f, 0.f, 0.f, 0.f};
    float bv[4];
#pragma unroll
    for (int kf = 0; kf < 4; ++kf) bv[kf] = bias[kf * 16 + lr];

#pragma unroll
    for (int r = 0; r < 4; ++r) {
        int n = n0 + w * 16 + lg * 4 + r;
        float sv[4];
        float m = -1e30f;
#pragma unroll
        for (int kf = 0; kf < 4; ++kf) { sv[kf] = acc[kf][r] + bv[kf]; m = fmaxf(m, sv[kf]); }
#pragma unroll
        for (int mask = 1; mask < 16; mask <<= 1)
            m = fmaxf(m, __shfl_xor(m, mask, 64));
        float sum = 0.f;
#pragma unroll
        for (int kf = 0; kf < 4; ++kf) { sv[kf] = __expf(sv[kf] - m); sum += sv[kf]; }
#pragma unroll
        for (int mask = 1; mask < 16; mask <<= 1)
            sum += __shfl_xor(sum, mask, 64);
        float inv = 1.0f / sum;
        bool valid = (n < NP);
#pragma unroll
        for (int kf = 0; kf < 4; ++kf) {
            pv[kf][r] = sv[kf] * inv;
            if (valid) part[kf] += pv[kf][r];
        }
    }
    // deterministic a_sum partial: reduce over lg (lane bits 4,5), per-wave slot
#pragma unroll
    for (int kf = 0; kf < 4; ++kf) {
        part[kf] += __shfl_xor(part[kf], 16, 64);
        part[kf] += __shfl_xor(part[kf], 32, 64);
    }
    if (lg == 0) {
#pragma unroll
        for (int kf = 0; kf < 4; ++kf) asw[w][kf * 16 + lr] = part[kf];
    }

    // bounce a -> [k][n] bf16 tile (aliases xbuf0: free after final compute)
    unsigned short* lb = (unsigned short*)lds;
    const int nl0 = w * 16 + lg * 4;
#pragma unroll
    for (int kf = 0; kf < 4; ++kf) {
        int krow = kf * 16 + lr;
#pragma unroll
        for (int rp = 0; rp < 2; ++rp) {
            unsigned v32 = cvt_pk_bf16(pv[kf][2 * rp], pv[kf][2 * rp + 1]);
            *(unsigned*)((char*)lb + krow * 128 +
                         ((nl0 * 2 + rp * 4) ^ ((krow & 7) << 4))) = v32;
        }
    }
    __syncthreads();
    for (int r2 = (t >> 3); r2 < 64; r2 += 32) {
        int n8 = (t & 7) * 8;
        if (n0 + n8 < NP) {
            int4 val = *(const int4*)((const char*)lb + r2 * 128 +
                                      ((n8 * 2) ^ ((r2 & 7) << 4)));
            *(int4*)(aT + ((size_t)b * NK + r2) * NP + n0 + n8) = val;
        }
    }
    if (t < 64) {
        float s = asw[0][t] + asw[1][t] + asw[2][t] + asw[3][t];  // fixed order
        a_sum_p[((size_t)b * 13 + blockIdx.x) * NK + t] = s;
    }
}

// ---------------------------------------------------------------------------
// K2: v[b][d][k] (bf16) = sum_n a[n][k]*x[n][d] + C[d][k]*a_sum[b][k]
// NOW 32d x 64k tiles, 128 threads (2 waves), grid 1024 -> ~4 blocks/CU
// (was 512 blocks = 2/CU, occupancy-limited). Per-wave fragment code is
// unchanged (each wave owns 16 d-cols). STAGE_A = 4 gload16/wave.
// Steady queue: [SA(it):4, LB(it+1):4, SA(it+1):4, LB(it+2):4] -> vmcnt(12).
// XCD: all 16 d-blocks of batch b on XCD b&7 (aT_b + v_b L2-resident).
// ---------------------------------------------------------------------------
__global__ __launch_bounds__(128) void k_vlad(
    const float* __restrict__ x, const unsigned short* __restrict__ aT,
    const float* __restrict__ Cm, const float* __restrict__ a_sum_p,
    unsigned short* __restrict__ v, const float* __restrict__ zpad,
    float* __restrict__ ssq_p)
{
    __shared__ __align__(16) char lds[16384];             // la dbuf 2 x 8KB
    __shared__ __align__(16) unsigned short lxT[4][1024]; // [wave*2+buf][16d x 64n]
    __shared__ float ssw[2][64];

    const int t = threadIdx.x;                   // 0..127
    const int w = t >> 6, l = t & 63, lr = l & 15, lg = l >> 4;
    // XCD-bijective decode: f = (b&7) + 8*(dgrp + 16*(b>>3))
    const int f = blockIdx.x;
    const int q = f >> 3;                        // 0..127
    const int dgrp = q & 15;                     // 0..15
    const int d0 = dgrp * 32;
    const int b  = (f & 7) + 8 * (q >> 4);
    const int np_ = l & 31, dq = l >> 5;

    const float* xb = x + (size_t)b * NP * ND;
    const unsigned short* ab = aT + (size_t)b * NK * NP;
    const float* xcol = xb + d0 + w * 16 + dq * 8;

    auto STAGE_A = [&](int n0, int buf) {
        char* base = lds + buf * 8192;
#pragma unroll
        for (int i = 0; i < 4; ++i) {
            int flat = t + i * 128;              // 0..511 chunks
            int k = flat >> 3, c = flat & 7;
            int cs = c ^ (k & 7);
            const void* src = (n0 + cs * 8 + 8 <= NP)
                              ? (const void*)(ab + (size_t)k * NP + n0 + cs * 8)
                              : (const void*)zpad;
            gload16(src, base + i * 2048 + w * 1024);
        }
    };

    float r0[2][8], r1[2][8];                    // two sets; indices compile-time
    auto LOAD_B = [&](int n0, int set) {
        int nlo = n0 + 2 * np_;
        int na = nlo < NP ? nlo : NP - 1;       // clamped rows multiply a=0
        int nb2 = nlo + 1 < NP ? nlo + 1 : NP - 1;
        *(f32x4*)&r0[set][0] = *(const f32x4*)(xcol + (size_t)na * ND);
        *(f32x4*)&r0[set][4] = *(const f32x4*)(xcol + (size_t)na * ND + 4);
        *(f32x4*)&r1[set][0] = *(const f32x4*)(xcol + (size_t)nb2 * ND);
        *(f32x4*)&r1[set][4] = *(const f32x4*)(xcol + (size_t)nb2 * ND + 4);
    };
    auto WRITE_B = [&](int buf, int set) {
        unsigned short* lt = lxT[w * 2 + buf];
#pragma unroll
        for (int jd = 0; jd < 8; ++jd) {
            int row = dq * 8 + jd;
            unsigned v32 = cvt_pk_bf16(r0[set][jd], r1[set][jd]);
            *(unsigned*)((char*)lt + row * 128 + ((np_ * 4) ^ ((row & 7) << 4))) = v32;
        }
    };

    f32x4 acc[4] = {};
    LOAD_B(0, 0);                                // tile 0 -> set0
    STAGE_A(0, 0);
    WRITE_B(0, 0);                               // reg-dep drains LB(0) (oldest)
    LOAD_B(64, 1);                               // tile 1 -> set1
#pragma unroll
    for (int it = 0; it < 13; ++it) {
        const int n0 = it * 64;
        if (it <= 10) {
            STAGE_A(n0 + 64, (it + 1) & 1);
            LOAD_B(n0 + 128, it & 1);            // tile it+2 -> set[it&1]
            VMCNT(12);
        } else if (it == 11) {
            STAGE_A(n0 + 64, (it + 1) & 1);
            VMCNT(8);
        } else {
            VMCNT(0);
        }
        BAR_HEAD();                              // la[it&1] ready
        const char* la = lds + (it & 1) * 8192;
        const unsigned short* lt = lxT[w * 2 + (it & 1)];
#pragma unroll
        for (int kk = 0; kk < 2; ++kk) {
            bf16x8 bfr = *(const bf16x8*)((const char*)lt + lr * 128 +
                                          ((kk * 64 + lg * 16) ^ ((lr & 7) << 4)));
#pragma unroll
            for (int kf = 0; kf < 4; ++kf) {
                int kr = kf * 16 + lr;
                bf16x8 afr = *(const bf16x8*)(la + kr * 128 +
                                              (((kk * 4 + lg) ^ (kr & 7)) * 16));
                acc[kf] = __builtin_amdgcn_mfma_f32_16x16x32_bf16(afr, bfr, acc[kf], 0, 0, 0);
            }
        }
        if (it < 12) WRITE_B((it + 1) & 1, (it + 1) & 1);  // tile it+1 (1 iter old)
        BAR_TAIL();                              // drain LDS pipe, then barrier
    }

    // epilogue: d = d0+w*16+lr (col), k = kf*16+lg*4..+3 (rows)
    const int dcol = d0 + w * 16 + lr;
#pragma unroll
    for (int kf = 0; kf < 4; ++kf) {
        int kb = kf * 16 + lg * 4;
        f32x4 s4 = {};
#pragma unroll
        for (int c = 0; c < 13; ++c)            // fixed-order a_sum (L2-hot)
            s4 += *(const f32x4*)(a_sum_p + ((size_t)b * 13 + c) * NK + kb);
        f32x4 c4 = *(const f32x4*)(Cm + (size_t)dcol * NK + kb);
        f32x4 o = acc[kf] + c4 * s4;
        // v stored bf16 (8B/lane); ssq from fp32 o (pre-rounding)
        uint2 pk;
        pk.x = cvt_pk_bf16(o[0], o[1]);
        pk.y = cvt_pk_bf16(o[2], o[3]);
        *(uint2*)(v + ((size_t)b * ND + dcol) * NK + kb) = pk;
        f32x4 qq = o * o;
#pragma unroll
        for (int m = 1; m < 16; m <<= 1) {
            qq[0] += __shfl_xor(qq[0], m, 64);
            qq[1] += __shfl_xor(qq[1], m, 64);
            qq[2] += __shfl_xor(qq[2], m, 64);
            qq[3] += __shfl_xor(qq[3], m, 64);
        }
        if (lr == 0) {
            ssw[w][kb + 0] = qq[0]; ssw[w][kb + 1] = qq[1];
            ssw[w][kb + 2] = qq[2]; ssw[w][kb + 3] = qq[3];
        }
    }
    __syncthreads();
    if (t < 64) {
        float s = ssw[0][t] + ssw[1][t];         // fixed order
        ssq_p[((size_t)b * 16 + dgrp) * NK + t] = s;
    }
}

// ---------------------------------------------------------------------------
// K3: scale-only normalize. grid 512, XCD-ALIGNED with k_vlad (block f ->
// XCD f&7 = b&7). Sums 16 ssq partials; reads v bf16, writes out fp32.
// ---------------------------------------------------------------------------
__global__ __launch_bounds__(256) void k_scale(
    const unsigned short* __restrict__ v, const float* __restrict__ ssq_p,
    float* __restrict__ out)
{
    __shared__ float scl[64];
    const int t = threadIdx.x;
    const int f = blockIdx.x;
    const int b  = (f & 7) + 8 * (f >> 6);      // XCD = f&7 = b&7 (matches k_vlad)
    const int dg = (f >> 3) & 7;

    if (t < 64) {
        float tot = 0.f;
#pragma unroll
        for (int c = 0; c < 16; ++c) tot += ssq_p[((size_t)b * 16 + c) * NK + t];
        float cc = tot / (tot + EPS_F);
        float g = cc;
#pragma unroll
        for (int mask = 1; mask < 64; mask <<= 1)
            g += __shfl_xor(g, mask, 64);
        scl[t] = 1.0f / (sqrtf(tot + EPS_F) * sqrtf(g + EPS_F));
    }
    __syncthreads();

    const unsigned short* vb = v + ((size_t)b * ND + dg * 64) * NK;
    float* ob = out + ((size_t)b * ND + dg * 64) * NK;
    f32x4 sc4 = *(const f32x4*)(&scl[(t & 15) * 4]);   // thread's k-quad fixed
#pragma unroll
    for (int i = 0; i < 4; ++i) {
        int idx = i * 256 + t;                  // quad index; idx&15 == t&15
        int row = idx >> 4;
        ushort4 pk = *(const ushort4*)(vb + row * NK + (t & 15) * 4);
        f32x4 val = { bf2f(pk.x), bf2f(pk.y), bf2f(pk.z), bf2f(pk.w) };
        *(f32x4*)(ob + row * NK + (t & 15) * 4) = val * sc4;
    }
}

// ---------------------------------------------------------------------------
extern "C" void kernel_launch(void* const* d_in, const int* in_sizes, int n_in,
                              void* d_out, int out_size, void* d_ws, size_t ws_size,
                              hipStream_t stream)
{
    const float* x    = (const float*)d_in[0];
    const float* Wm   = (const float*)d_in[1];
    const float* bias = (const float*)d_in[2];
    const float* Cm   = (const float*)d_in[3];
    float* out = (float*)d_out;

    char* ws = (char*)d_ws;
    unsigned short* aT = (unsigned short*)ws;                 // 6,422,528 B
    char* p = ws + (size_t)NB * NK * NP * 2;
    float* a_sum_p = (float*)p;                               // 212,992 B
    p += (size_t)NB * 13 * NK * 4;
    unsigned short* v = (unsigned short*)p;                   // 4,194,304 B (bf16)
    p += (size_t)NB * ND * NK * 2;
    unsigned short* Wt = (unsigned short*)p;                  // 65,536 B
    p += (size_t)NK * ND * 2;
    float* zpad = (float*)p;                                  // 256 B
    p += 256;
    float* ssq_p = (float*)p;                                 // 64*16*64*4 = 262,144 B

    hipLaunchKernelGGL(k_wt, dim3(128), dim3(256), 0, stream, Wm, Wt, zpad);
    dim3 g1((NP + 63) / 64, NB);
    hipLaunchKernelGGL(k_assign, g1, dim3(256), 0, stream, x, Wt, bias, aT, a_sum_p);
    hipLaunchKernelGGL(k_vlad, dim3(1024), dim3(128), 0, stream, x, aT, Cm, a_sum_p, v, zpad, ssq_p);
    hipLaunchKernelGGL(k_scale, dim3(512), dim3(256), 0, stream, v, ssq_p, out);
}

// Round 13
// 58.968 us; speedup vs baseline: 1.0729x; 1.0729x over previous
//
#include <hip/hip_runtime.h>
#include <math.h>

#define NB 64
#define NP 784      // 28*28
#define ND 512
#define NK 64
#define EPS_F 1e-12f

typedef float f32x4 __attribute__((ext_vector_type(4)));
typedef short bf16x8 __attribute__((ext_vector_type(8)));

// Leading barrier: memory-clobber fences pin all LDS/global memory ops.
#define BAR_HEAD() { asm volatile("" ::: "memory"); \
                     __builtin_amdgcn_s_barrier(); \
                     asm volatile("" ::: "memory"); }
// Trailing barrier: rule #18 — "memory" does NOT order register-only MFMA;
// sched_barrier(0) blocks ALL migration; lgkmcnt(0) drains the LDS pipe
// before any wave crosses.
#define BAR_TAIL() { __builtin_amdgcn_sched_barrier(0); \
                     asm volatile("s_waitcnt lgkmcnt(0)" ::: "memory"); \
                     __builtin_amdgcn_sched_barrier(0); \
                     __builtin_amdgcn_s_barrier(); \
                     __builtin_amdgcn_sched_barrier(0); }
#define VMCNT(n) asm volatile("s_waitcnt vmcnt(" #n ")" ::: "memory")

__device__ __forceinline__ unsigned short f2bf(float f) {
    unsigned u = __builtin_bit_cast(unsigned, f);
    u += 0x7fffu + ((u >> 16) & 1u);
    return (unsigned short)(u >> 16);
}

__device__ __forceinline__ unsigned cvt_pk_bf16(float lo, float hi) {
    unsigned r;
    asm("v_cvt_pk_bf16_f32 %0, %1, %2" : "=v"(r) : "v"(lo), "v"(hi));
    return r;
}

__device__ __forceinline__ float bf2f(unsigned short u) {
    unsigned x = (unsigned)u << 16;
    return __builtin_bit_cast(float, x);
}

__device__ __forceinline__ bf16x8 pack8(const float* s) {
    union { unsigned u[4]; bf16x8 v; } r;
#pragma unroll
    for (int i = 0; i < 4; ++i) r.u[i] = cvt_pk_bf16(s[2 * i], s[2 * i + 1]);
    return r.v;
}

// async 16B global->LDS (dest wave-uniform; HW adds lane*16)
__device__ __forceinline__ void gload16(const void* g, void* l) {
    __builtin_amdgcn_global_load_lds(
        (const __attribute__((address_space(1))) unsigned*)g,
        (__attribute__((address_space(3))) unsigned*)l, 16, 0, 0);
}

// ---------------------------------------------------------------------------
// K0: Wt[k][d] bf16 = W[d][k] fp32; zero zpad.
// ---------------------------------------------------------------------------
__global__ __launch_bounds__(256) void k_wt(const float* __restrict__ W,
                                            unsigned short* __restrict__ Wt,
                                            float* __restrict__ zpad)
{
    int idx = blockIdx.x * 256 + threadIdx.x;   // 0..32767
    int k = idx >> 9, d = idx & 511;
    Wt[idx] = f2bf(W[(size_t)d * NK + k]);
    if (idx < 64) zpad[idx] = 0.f;
}

// ---------------------------------------------------------------------------
// K1: s = x.W + bias ; a = softmax_k(s) ; aT[b][k][n] bf16 ;
// a_sum_p[b][blk][k] (deterministic partials). grid (13,64), 4 waves.
// Tile 64n x 64k, BK=32, 16 steps, TRIPLE-buffered gload_lds staging:
// tile s+2 issued at iter s -> 2 iterations of HBM-latency cover.
// Queue at iter s: [T(s):3?, T(s+1):3, T(s+2):3] -> vmcnt(6); tail 3/0.
// LDS 36.9KB -> 4 blocks/CU (all 832 co-resident).
// ---------------------------------------------------------------------------
__global__ __launch_bounds__(256) void k_assign(
    const float* __restrict__ x, const unsigned short* __restrict__ Wt,
    const float* __restrict__ bias, unsigned short* __restrict__ aT,
    float* __restrict__ a_sum_p)
{
    // [0,24576) xbuf x3 (8KB each) | [24576,36864) wbuf x3 (4KB each)
    __shared__ __align__(16) char lds[36864];
    __shared__ float asw[4][64];

    const int t = threadIdx.x;
    const int w = t >> 6, l = t & 63, lr = l & 15, lg = l >> 4;
    const int b = blockIdx.y, n0 = blockIdx.x * 64;

    const float* xb = x + (size_t)b * NP * ND;

    auto STAGE = [&](int d0, int buf) {
        char* xdst = lds + buf * 8192 + w * 1024;
        char* wdst = lds + 24576 + buf * 4096 + w * 1024;
#pragma unroll
        for (int i = 0; i < 2; ++i) {            // x tile: [64n][8 chunks] fp32
            int flat = t + i * 256;
            int n = flat >> 3, c = flat & 7;
            int cs = c ^ (n & 7);
            int ng = n0 + n; if (ng >= NP) ng = NP - 1;   // dup rows discarded later
            gload16(xb + (size_t)ng * ND + d0 + cs * 4, xdst + i * 4096);
        }
        {                                         // Wt tile: [64k][4 chunks] bf16
            int k = t >> 2, c = t & 3;
            int cs = c ^ (k & 3);
            gload16(Wt + (size_t)k * ND + d0 + cs * 8, wdst);
        }
    };

    f32x4 acc[4] = {};
    STAGE(0, 0);
    STAGE(32, 1);
#pragma unroll
    for (int s = 0; s < 16; ++s) {
        if (s < 14)      { STAGE((s + 2) * 32, (s + 2) % 3); VMCNT(6); }
        else if (s == 14) { VMCNT(3); }
        else              { VMCNT(0); }
        BAR_HEAD();                              // buf[s%3] ready for all waves
        const char* xT = lds + (s % 3) * 8192;
        const char* wT = lds + 24576 + (s % 3) * 4096;
        const int nr = w * 16 + lr;
        const int cc = lg * 2;
        float av[8];
        *(f32x4*)&av[0] = *(const f32x4*)(xT + nr * 128 + ((cc ^ (nr & 7)) * 16));
        *(f32x4*)&av[4] = *(const f32x4*)(xT + nr * 128 + (((cc + 1) ^ (nr & 7)) * 16));
        bf16x8 af = pack8(av);
#pragma unroll
        for (int kf = 0; kf < 4; ++kf) {
            int kr = kf * 16 + lr;
            bf16x8 bfr = *(const bf16x8*)(wT + kr * 64 + ((lg ^ (kr & 3)) * 16));
            acc[kf] = __builtin_amdgcn_mfma_f32_16x16x32_bf16(af, bfr, acc[kf], 0, 0, 0);
        }
        BAR_TAIL();                              // drain LDS pipe, then barrier
    }

    // softmax over k: lane holds k = kf*16+lr, n = n0 + w*16 + lg*4 + r
    float pv[4][4];
    float part[4] = {0.f, 0.f, 0.f, 0.f};
    float bv[4];
#pragma unroll
    for (int kf = 0; kf < 4; ++kf) bv[kf] = bias[kf * 16 + lr];

#pragma unroll
    for (int r = 0; r < 4; ++r) {
        int n = n0 + w * 16 + lg * 4 + r;
        float sv[4];
        float m = -1e30f;
#pragma unroll
        for (int kf = 0; kf < 4; ++kf) { sv[kf] = acc[kf][r] + bv[kf]; m = fmaxf(m, sv[kf]); }
#pragma unroll
        for (int mask = 1; mask < 16; mask <<= 1)
            m = fmaxf(m, __shfl_xor(m, mask, 64));
        float sum = 0.f;
#pragma unroll
        for (int kf = 0; kf < 4; ++kf) { sv[kf] = __expf(sv[kf] - m); sum += sv[kf]; }
#pragma unroll
        for (int mask = 1; mask < 16; mask <<= 1)
            sum += __shfl_xor(sum, mask, 64);
        float inv = 1.0f / sum;
        bool valid = (n < NP);
#pragma unroll
        for (int kf = 0; kf < 4; ++kf) {
            pv[kf][r] = sv[kf] * inv;
            if (valid) part[kf] += pv[kf][r];
        }
    }
    // deterministic a_sum partial: reduce over lg (lane bits 4,5), per-wave slot
#pragma unroll
    for (int kf = 0; kf < 4; ++kf) {
        part[kf] += __shfl_xor(part[kf], 16, 64);
        part[kf] += __shfl_xor(part[kf], 32, 64);
    }
    if (lg == 0) {
#pragma unroll
        for (int kf = 0; kf < 4; ++kf) asw[w][kf * 16 + lr] = part[kf];
    }

    // bounce a -> [k][n] bf16 tile (aliases xbuf0: free after final compute)
    unsigned short* lb = (unsigned short*)lds;
    const int nl0 = w * 16 + lg * 4;
#pragma unroll
    for (int kf = 0; kf < 4; ++kf) {
        int krow = kf * 16 + lr;
#pragma unroll
        for (int rp = 0; rp < 2; ++rp) {
            unsigned v32 = cvt_pk_bf16(pv[kf][2 * rp], pv[kf][2 * rp + 1]);
            *(unsigned*)((char*)lb + krow * 128 +
                         ((nl0 * 2 + rp * 4) ^ ((krow & 7) << 4))) = v32;
        }
    }
    __syncthreads();
    for (int r2 = (t >> 3); r2 < 64; r2 += 32) {
        int n8 = (t & 7) * 8;
        if (n0 + n8 < NP) {
            int4 val = *(const int4*)((const char*)lb + r2 * 128 +
                                      ((n8 * 2) ^ ((r2 & 7) << 4)));
            *(int4*)(aT + ((size_t)b * NK + r2) * NP + n0 + n8) = val;
        }
    }
    if (t < 64) {
        float s = asw[0][t] + asw[1][t] + asw[2][t] + asw[3][t];  // fixed order
        a_sum_p[((size_t)b * 13 + blockIdx.x) * NK + t] = s;
    }
}

// ---------------------------------------------------------------------------
// K2 (round-11 optimum): v[b][d][k] (bf16) = sum_n a[n][k]*x[n][d] +
// C[d][k]*a_sum[b][k]. 64d x 64k tiles, 256 threads, grid 512.
// Depth-2 register pipeline for x (LOAD_B). ssq partials from fp32 acc.
// XCD: block f -> XCD f&7 = b&7; batch's aT/v L2-resident there.
// ---------------------------------------------------------------------------
__global__ __launch_bounds__(256) void k_vlad(
    const float* __restrict__ x, const unsigned short* __restrict__ aT,
    const float* __restrict__ Cm, const float* __restrict__ a_sum_p,
    unsigned short* __restrict__ v, const float* __restrict__ zpad,
    float* __restrict__ ssq_p)
{
    __shared__ __align__(16) char lds[16384];             // la dbuf 2 x 8KB
    __shared__ __align__(16) unsigned short lxT[8][1024]; // [wave*2+buf][16d x 64n]
    __shared__ float ssw[4][64];

    const int t = threadIdx.x;
    const int w = t >> 6, l = t & 63, lr = l & 15, lg = l >> 4;
    // XCD-bijective decode: same-batch d-blocks land on one XCD
    const int f = blockIdx.x;
    const int q = f >> 3;
    const int dgrp = q & 7;
    const int d0 = dgrp * 64;
    const int b  = (f & 7) + 8 * (q >> 3);
    const int np_ = l & 31, dq = l >> 5;

    const float* xb = x + (size_t)b * NP * ND;
    const unsigned short* ab = aT + (size_t)b * NK * NP;
    const float* xcol = xb + d0 + w * 16 + dq * 8;

    auto STAGE_A = [&](int n0, int buf) {
        char* dst = lds + buf * 8192 + w * 1024;
#pragma unroll
        for (int i = 0; i < 2; ++i) {
            int flat = t + i * 256;
            int k = flat >> 3, c = flat & 7;
            int cs = c ^ (k & 7);
            const void* src = (n0 + cs * 8 + 8 <= NP)
                              ? (const void*)(ab + (size_t)k * NP + n0 + cs * 8)
                              : (const void*)zpad;
            gload16(src, dst + i * 4096);
        }
    };

    float r0[2][8], r1[2][8];                    // two sets; indices compile-time
    auto LOAD_B = [&](int n0, int set) {
        int nlo = n0 + 2 * np_;
        int na = nlo < NP ? nlo : NP - 1;       // clamped rows multiply a=0
        int nb2 = nlo + 1 < NP ? nlo + 1 : NP - 1;
        *(f32x4*)&r0[set][0] = *(const f32x4*)(xcol + (size_t)na * ND);
        *(f32x4*)&r0[set][4] = *(const f32x4*)(xcol + (size_t)na * ND + 4);
        *(f32x4*)&r1[set][0] = *(const f32x4*)(xcol + (size_t)nb2 * ND);
        *(f32x4*)&r1[set][4] = *(const f32x4*)(xcol + (size_t)nb2 * ND + 4);
    };
    auto WRITE_B = [&](int buf, int set) {
        unsigned short* lt = lxT[w * 2 + buf];
#pragma unroll
        for (int jd = 0; jd < 8; ++jd) {
            int row = dq * 8 + jd;
            unsigned v32 = cvt_pk_bf16(r0[set][jd], r1[set][jd]);
            *(unsigned*)((char*)lt + row * 128 + ((np_ * 4) ^ ((row & 7) << 4))) = v32;
        }
    };

    f32x4 acc[4] = {};
    LOAD_B(0, 0);                                // tile 0 -> set0
    STAGE_A(0, 0);
    WRITE_B(0, 0);                               // auto-waits LB(0)
    LOAD_B(64, 1);                               // tile 1 -> set1
#pragma unroll
    for (int it = 0; it < 13; ++it) {
        const int n0 = it * 64;
        if (it <= 10) {
            STAGE_A(n0 + 64, (it + 1) & 1);
            LOAD_B(n0 + 128, it & 1);            // tile it+2 -> set[it&1]
            VMCNT(10);
        } else if (it == 11) {
            STAGE_A(n0 + 64, (it + 1) & 1);
            VMCNT(6);
        } else {
            VMCNT(0);
        }
        BAR_HEAD();                              // la[it&1] ready
        const char* la = lds + (it & 1) * 8192;
        const unsigned short* lt = lxT[w * 2 + (it & 1)];
#pragma unroll
        for (int kk = 0; kk < 2; ++kk) {
            bf16x8 bfr = *(const bf16x8*)((const char*)lt + lr * 128 +
                                          ((kk * 64 + lg * 16) ^ ((lr & 7) << 4)));
#pragma unroll
            for (int kf = 0; kf < 4; ++kf) {
                int kr = kf * 16 + lr;
                bf16x8 afr = *(const bf16x8*)(la + kr * 128 +
                                              (((kk * 4 + lg) ^ (kr & 7)) * 16));
                acc[kf] = __builtin_amdgcn_mfma_f32_16x16x32_bf16(afr, bfr, acc[kf], 0, 0, 0);
            }
        }
        if (it < 12) WRITE_B((it + 1) & 1, (it + 1) & 1);  // tile it+1 (1 iter old)
        BAR_TAIL();                              // drain LDS pipe, then barrier
    }

    // epilogue: d = d0+w*16+lr (col), k = kf*16+lg*4..+3 (rows)
    const int dcol = d0 + w * 16 + lr;
#pragma unroll
    for (int kf = 0; kf < 4; ++kf) {
        int kb = kf * 16 + lg * 4;
        f32x4 s4 = {};
#pragma unroll
        for (int c = 0; c < 13; ++c)            // fixed-order a_sum (L2-hot)
            s4 += *(const f32x4*)(a_sum_p + ((size_t)b * 13 + c) * NK + kb);
        f32x4 c4 = *(const f32x4*)(Cm + (size_t)dcol * NK + kb);
        f32x4 o = acc[kf] + c4 * s4;
        // v stored bf16 (8B/lane); ssq from fp32 o (pre-rounding)
        uint2 pk;
        pk.x = cvt_pk_bf16(o[0], o[1]);
        pk.y = cvt_pk_bf16(o[2], o[3]);
        *(uint2*)(v + ((size_t)b * ND + dcol) * NK + kb) = pk;
        f32x4 qq = o * o;
#pragma unroll
        for (int m = 1; m < 16; m <<= 1) {
            qq[0] += __shfl_xor(qq[0], m, 64);
            qq[1] += __shfl_xor(qq[1], m, 64);
            qq[2] += __shfl_xor(qq[2], m, 64);
            qq[3] += __shfl_xor(qq[3], m, 64);
        }
        if (lr == 0) {
            ssw[w][kb + 0] = qq[0]; ssw[w][kb + 1] = qq[1];
            ssw[w][kb + 2] = qq[2]; ssw[w][kb + 3] = qq[3];
        }
    }
    __syncthreads();
    if (t < 64) {
        float s = ssw[0][t] + ssw[1][t] + ssw[2][t] + ssw[3][t];  // fixed order
        ssq_p[((size_t)b * 8 + dgrp) * NK + t] = s;
    }
}

// ---------------------------------------------------------------------------
// K3: scale-only normalize. grid 512, XCD-ALIGNED with k_vlad (block f ->
// XCD f&7 = b&7). Sums 8 ssq partials; reads v bf16, writes out fp32.
// ---------------------------------------------------------------------------
__global__ __launch_bounds__(256) void k_scale(
    const unsigned short* __restrict__ v, const float* __restrict__ ssq_p,
    float* __restrict__ out)
{
    __shared__ float scl[64];
    const int t = threadIdx.x;
    const int f = blockIdx.x;
    const int b  = (f & 7) + 8 * (f >> 6);      // XCD = f&7 = b&7 (matches k_vlad)
    const int dg = (f >> 3) & 7;

    if (t < 64) {
        float tot = 0.f;
#pragma unroll
        for (int c = 0; c < 8; ++c) tot += ssq_p[((size_t)b * 8 + c) * NK + t];
        float cc = tot / (tot + EPS_F);
        float g = cc;
#pragma unroll
        for (int mask = 1; mask < 64; mask <<= 1)
            g += __shfl_xor(g, mask, 64);
        scl[t] = 1.0f / (sqrtf(tot + EPS_F) * sqrtf(g + EPS_F));
    }
    __syncthreads();

    const unsigned short* vb = v + ((size_t)b * ND + dg * 64) * NK;
    float* ob = out + ((size_t)b * ND + dg * 64) * NK;
    f32x4 sc4 = *(const f32x4*)(&scl[(t & 15) * 4]);   // thread's k-quad fixed
#pragma unroll
    for (int i = 0; i < 4; ++i) {
        int idx = i * 256 + t;                  // quad index; idx&15 == t&15
        int row = idx >> 4;
        ushort4 pk = *(const ushort4*)(vb + row * NK + (t & 15) * 4);
        f32x4 val = { bf2f(pk.x), bf2f(pk.y), bf2f(pk.z), bf2f(pk.w) };
        *(f32x4*)(ob + row * NK + (t & 15) * 4) = val * sc4;
    }
}

// ---------------------------------------------------------------------------
extern "C" void kernel_launch(void* const* d_in, const int* in_sizes, int n_in,
                              void* d_out, int out_size, void* d_ws, size_t ws_size,
                              hipStream_t stream)
{
    const float* x    = (const float*)d_in[0];
    const float* Wm   = (const float*)d_in[1];
    const float* bias = (const float*)d_in[2];
    const float* Cm   = (const float*)d_in[3];
    float* out = (float*)d_out;

    char* ws = (char*)d_ws;
    unsigned short* aT = (unsigned short*)ws;                 // 6,422,528 B
    char* p = ws + (size_t)NB * NK * NP * 2;
    float* a_sum_p = (float*)p;                               // 212,992 B
    p += (size_t)NB * 13 * NK * 4;
    unsigned short* v = (unsigned short*)p;                   // 4,194,304 B (bf16)
    p += (size_t)NB * ND * NK * 2;
    unsigned short* Wt = (unsigned short*)p;                  // 65,536 B
    p += (size_t)NK * ND * 2;
    float* zpad = (float*)p;                                  // 256 B
    p += 256;
    float* ssq_p = (float*)p;                                 // 131,072 B

    hipLaunchKernelGGL(k_wt, dim3(128), dim3(256), 0, stream, Wm, Wt, zpad);
    dim3 g1((NP + 63) / 64, NB);
    hipLaunchKernelGGL(k_assign, g1, dim3(256), 0, stream, x, Wt, bias, aT, a_sum_p);
    hipLaunchKernelGGL(k_vlad, dim3(512), dim3(256), 0, stream, x, aT, Cm, a_sum_p, v, zpad, ssq_p);
    hipLaunchKernelGGL(k_scale, dim3(512), dim3(256), 0, stream, v, ssq_p, out);
}